// Round 5
// baseline (175.939 us; speedup 1.0000x reference)
//
#include <hip/hip_runtime.h>

typedef unsigned short u16;
typedef short bfrag __attribute__((ext_vector_type(8)));   // 8 x bf16 (4 VGPRs)
typedef float facc  __attribute__((ext_vector_type(4)));   // 4 x f32
typedef float f16x  __attribute__((ext_vector_type(16)));  // 16 x f32 (32x32 acc)

__device__ __forceinline__ u16 f2bf(float f){
  union { float f; unsigned u; } v; v.f = f;
  unsigned r = v.u + 0x7fffu + ((v.u >> 16) & 1u);
  return (u16)(r >> 16);
}

__device__ __forceinline__ unsigned cvt_pk_bf16(float lo, float hi){
  unsigned d;
  asm("v_cvt_pk_bf16_f32 %0, %1, %2" : "=v"(d) : "v"(lo), "v"(hi));
  return d;
}

__device__ __forceinline__ void gl_lds16(const void* g, void* l){
  __builtin_amdgcn_global_load_lds(
      (const __attribute__((address_space(1))) unsigned int*)g,
      (__attribute__((address_space(3))) unsigned int*)l,
      16, 0, 0);
}

// ---------------- fp32 -> bf16 conversion ----------------
__global__ __launch_bounds__(256) void cvt_kernel(const float* __restrict__ src,
                                                  u16* __restrict__ dst, int n){
  int i = (blockIdx.x * 256 + threadIdx.x) * 4;
  if (i < n){
    float4 f = *(const float4*)(src + i);
    ushort4 o;
    o.x = f2bf(f.x); o.y = f2bf(f.y); o.z = f2bf(f.z); o.w = f2bf(f.w);
    *(ushort4*)(dst + i) = o;
  }
}

// ---------------- bf16 GEMM: C[m,n] = sum_k A[m,k]*B[n,k] + bias[n] ----------------
__device__ __forceinline__ void stage_tile(const u16* __restrict__ G, u16* lds,
                                           int row0, int k0, int K, int tid){
  #pragma unroll
  for (int c = 0; c < 2; ++c){
    int e = c * 2048 + tid * 8;
    int row = e >> 5, col = e & 31;
    gl_lds16(G + (size_t)(row0 + row) * K + k0 + col, lds + c * 2048 + (tid >> 6) * 512);
  }
}

template<int EPI>
__global__ __launch_bounds__(256) void gemm_bt(
    const u16* __restrict__ A, const u16* __restrict__ B,
    const float* __restrict__ bias, float* __restrict__ Cf,
    u16* __restrict__ qkv, int M, int N, int K)
{
  __shared__ u16 Ash[2][4096];
  __shared__ u16 Bsh[2][4096];
  const int tid = threadIdx.x, lane = tid & 63;
  const int w = tid >> 6, wm = w >> 1, wn = w & 1;
  const int cl = lane & 15, g8 = (lane >> 4) * 8;
  const int n0 = blockIdx.x * 128, m0 = blockIdx.y * 128;

  facc acc[4][4];
  #pragma unroll
  for (int mi = 0; mi < 4; ++mi)
    #pragma unroll
    for (int ni = 0; ni < 4; ++ni)
      acc[mi][ni] = (facc){0.f, 0.f, 0.f, 0.f};

  const int NT = K >> 5;
  stage_tile(A, Ash[0], m0, 0, K, tid);
  stage_tile(B, Bsh[0], n0, 0, K, tid);
  __syncthreads();
  int cur = 0;
  for (int kt = 0; kt < NT; ++kt){
    if (kt + 1 < NT){
      stage_tile(A, Ash[cur ^ 1], m0, (kt + 1) << 5, K, tid);
      stage_tile(B, Bsh[cur ^ 1], n0, (kt + 1) << 5, K, tid);
    }
    const u16* As = Ash[cur]; const u16* Bs = Bsh[cur];
    bfrag af[4], bfr[4];
    #pragma unroll
    for (int mi = 0; mi < 4; ++mi)
      af[mi] = *(const bfrag*)&As[(wm * 64 + mi * 16 + cl) * 32 + g8];
    #pragma unroll
    for (int ni = 0; ni < 4; ++ni)
      bfr[ni] = *(const bfrag*)&Bs[(wn * 64 + ni * 16 + cl) * 32 + g8];
    #pragma unroll
    for (int mi = 0; mi < 4; ++mi)
      #pragma unroll
      for (int ni = 0; ni < 4; ++ni)
        acc[mi][ni] = __builtin_amdgcn_mfma_f32_16x16x32_bf16(af[mi], bfr[ni], acc[mi][ni], 0, 0, 0);
    __syncthreads();
    cur ^= 1;
  }

  const int r0 = (lane >> 4) * 4;
  #pragma unroll
  for (int mi = 0; mi < 4; ++mi){
    const int mbase = m0 + wm * 64 + mi * 16 + r0;
    #pragma unroll
    for (int ni = 0; ni < 4; ++ni){
      const int n = n0 + wn * 64 + ni * 16 + cl;
      const float bv = bias[n];
      #pragma unroll
      for (int j = 0; j < 4; ++j){
        float v = acc[mi][ni][j] + bv;
        const int mm = mbase + j;
        if (EPI == 0){
          Cf[(size_t)mm * N + n] = v;
        } else {
          const int part = n >> 10, rest = n & 1023;
          const int h = rest >> 6, d = rest & 63;
          const int bb = mm >> 11, s = mm & 2047;
          // fold 1/sqrt(dh)=1/8 AND log2(e) into q so attention uses exp2 directly
          if (part == 0) v *= 0.18033688011112042f;
          qkv[(size_t)part * 4194304 + (size_t)((bb * 16 + h) * 2048 + s) * 64 + d] = f2bf(v);
        }
      }
    }
  }
}

// ---------------- swapped-role causal flash attention (32x32 MFMA, in-reg P) ----
// out[i] = sum_{j<=i} softmax_j( Kproj[i] . Qproj[j]*log2e/8 ) * V[j], exp2 domain.
// S^T = mfma(K_rows, Q_rows): lane owns col i = lane&31; j lives in regs.
__global__ __launch_bounds__(128, 2) void attn_kernel(
    const u16* __restrict__ qarr, const u16* __restrict__ karr,
    const u16* __restrict__ varr, u16* __restrict__ aout,
    const int* __restrict__ cmask)
{
  __shared__ u16 vt_lds[2][4096];               // V^T [d][j], XOR-swizzled, dbuf
  const int tid = threadIdx.x, lane = tid & 63, w = tid >> 6;
  const int il = lane & 31, hi = lane >> 5;
  const int bh = blockIdx.x;                    // bh -> XCD (K/V/Q L2-resident)
  const int bi = 31 - (int)blockIdx.y;          // heavy tiles dispatch first
  const int i0 = bi * 64 + w * 32;
  const u16* Qh = karr + (size_t)bh * 131072;   // output rows come from k-proj
  const u16* Kh = qarr + (size_t)bh * 131072;   // keys are q-proj (pre-scaled)
  const u16* Vh = varr + (size_t)bh * 131072;
  const bool do_mask = (cmask[0] != 0);

  // persistent Q B-frags: bq[kt] holds Q[i0+il][kt*16 + 8*hi + e]
  bfrag bq[4];
  #pragma unroll
  for (int kt = 0; kt < 4; ++kt)
    bq[kt] = *(const bfrag*)(Qh + (size_t)(i0 + il) * 64 + kt * 16 + hi * 8);

  f16x o0, o1, lacc;
  #pragma unroll
  for (int r = 0; r < 16; ++r){ o0[r] = 0.f; o1[r] = 0.f; lacc[r] = 0.f; }
  float m_s = -1e30f;

  bfrag ones;
  #pragma unroll
  for (int e = 0; e < 8; ++e) ones[e] = (short)0x3F80;  // bf16 1.0

  const int c8 = tid & 7, j16 = tid >> 3;
  uint4 va[4];
  auto ldV = [&](int jt){
    #pragma unroll
    for (int r = 0; r < 4; ++r)
      va[r] = *(const uint4*)(Vh + (size_t)(jt * 64 + j16 + 16 * r) * 64 + c8 * 8);
  };
  auto stV = [&](int buf){
    u16* dst = vt_lds[buf];
    #pragma unroll
    for (int r = 0; r < 4; ++r){
      const int j = j16 + 16 * r;
      const u16* pv = (const u16*)&va[r];
      #pragma unroll
      for (int e = 0; e < 8; ++e){
        const int idx = (e + c8) & 7;             // rotated: conflict-free banks
        const int d = c8 * 8 + idx;               // d&7 == idx
        dst[(d * 64 + j) ^ (idx << 3)] = pv[idx]; // T2 XOR-swizzle
      }
    }
  };

  const int njt = do_mask ? (bi + 1) : 32;
  ldV(0); stV(0);
  __syncthreads();
  int cur = 0;

  for (int jt = 0; jt < njt; ++jt){
    const bool more = (jt + 1 < njt);
    if (more) ldV(jt + 1);                        // T14: issue next-tile loads early

    // S^T = K . Q^T  (two 32x32 j-subtiles, K straight from global/L2)
    f16x s0, s1;
    #pragma unroll
    for (int r = 0; r < 16; ++r){ s0[r] = 0.f; s1[r] = 0.f; }
    const u16* Kt = Kh + (size_t)jt * 4096;
    __builtin_amdgcn_s_setprio(1);
    #pragma unroll
    for (int kt = 0; kt < 4; ++kt){
      bfrag ak0 = *(const bfrag*)(Kt + (size_t)il * 64 + kt * 16 + hi * 8);
      bfrag ak1 = *(const bfrag*)(Kt + (size_t)(32 + il) * 64 + kt * 16 + hi * 8);
      s0 = __builtin_amdgcn_mfma_f32_32x32x16_bf16(ak0, bq[kt], s0, 0, 0, 0);
      s1 = __builtin_amdgcn_mfma_f32_32x32x16_bf16(ak1, bq[kt], s1, 0, 0, 0);
    }
    __builtin_amdgcn_s_setprio(0);

    if (do_mask && jt == bi){                     // diagonal tile: mask j > i
      const int ib = w * 32 + il;
      #pragma unroll
      for (int r = 0; r < 16; ++r){
        const int qj = (r & 3) + 8 * (r >> 2) + 4 * hi;
        if (qj > ib)      s0[r] = -1e30f;
        if (qj + 32 > ib) s1[r] = -1e30f;
      }
    }

    // row max: 31 in-lane fmax + 1 permlane32_swap across j-halves
    float tmax = s0[0];
    #pragma unroll
    for (int r = 1; r < 16; ++r) tmax = fmaxf(tmax, s0[r]);
    #pragma unroll
    for (int r = 0; r < 16; ++r) tmax = fmaxf(tmax, s1[r]);
    {
      auto tt = __builtin_amdgcn_permlane32_swap(__float_as_uint(tmax),
                                                 __float_as_uint(tmax), false, false);
      tmax = fmaxf(__uint_as_float(tt[0]), __uint_as_float(tt[1]));
    }
    if (__any(tmax - m_s > 8.0f)){                // defer-max (THR=8)
      const float nm = fmaxf(m_s, tmax);
      const float sc = __builtin_amdgcn_exp2f(m_s - nm);
      m_s = nm;
      #pragma unroll
      for (int r = 0; r < 16; ++r){
        const float scb = __shfl(sc, (r & 3) + 8 * (r >> 2) + 4 * hi, 64);
        lacc[r] *= scb; o0[r] *= scb; o1[r] *= scb;
      }
    }
    // P = exp2(S - m), in place
    #pragma unroll
    for (int r = 0; r < 16; ++r) s0[r] = __builtin_amdgcn_exp2f(s0[r] - m_s);
    #pragma unroll
    for (int r = 0; r < 16; ++r) s1[r] = __builtin_amdgcn_exp2f(s1[r] - m_s);

    // T12: cvt_pk + permlane32_swap -> PV A-frags; l via mfma against ones.
    // swap(a, b) semantics: a.hi <-> b.lo; ret[0]={a.lo,b.lo}, ret[1]={a.hi,b.hi}.
    #pragma unroll
    for (int kt = 0; kt < 4; ++kt){
      const int q0 = 8 * (kt & 1);
      unsigned a0, a1, b0, b1;
      if (kt < 2){
        a0 = cvt_pk_bf16(s0[q0],     s0[q0 + 1]);
        a1 = cvt_pk_bf16(s0[q0 + 2], s0[q0 + 3]);
        b0 = cvt_pk_bf16(s0[q0 + 4], s0[q0 + 5]);
        b1 = cvt_pk_bf16(s0[q0 + 6], s0[q0 + 7]);
      } else {
        a0 = cvt_pk_bf16(s1[q0],     s1[q0 + 1]);
        a1 = cvt_pk_bf16(s1[q0 + 2], s1[q0 + 3]);
        b0 = cvt_pk_bf16(s1[q0 + 4], s1[q0 + 5]);
        b1 = cvt_pk_bf16(s1[q0 + 6], s1[q0 + 7]);
      }
      auto r0 = __builtin_amdgcn_permlane32_swap(a0, b0, false, false);
      auto r1 = __builtin_amdgcn_permlane32_swap(a1, b1, false, false);
      union { bfrag f; unsigned u[4]; } pa;
      pa.u[0] = r0[0]; pa.u[1] = r1[0]; pa.u[2] = r0[1]; pa.u[3] = r1[1];

      const int vb = kt * 16 + hi * 8;
      bfrag v0 = *(const bfrag*)&vt_lds[cur][(il * 64 + vb) ^ ((il & 7) << 3)];
      bfrag v1 = *(const bfrag*)&vt_lds[cur][((32 + il) * 64 + vb) ^ ((il & 7) << 3)];
      lacc = __builtin_amdgcn_mfma_f32_32x32x16_bf16(pa.f, ones, lacc, 0, 0, 0);
      __builtin_amdgcn_s_setprio(1);
      o0 = __builtin_amdgcn_mfma_f32_32x32x16_bf16(pa.f, v0, o0, 0, 0, 0);
      o1 = __builtin_amdgcn_mfma_f32_32x32x16_bf16(pa.f, v1, o1, 0, 0, 0);
      __builtin_amdgcn_s_setprio(0);
    }

    if (more){                                    // write prefetched V, one barrier
      stV(cur ^ 1);
      __syncthreads();
      cur ^= 1;
    }
  }

  // epilogue: rows m=(r&3)+8(r>>2)+4hi live in regs; lacc has matching layout
  const int bb = bh >> 4, h = bh & 15;
  #pragma unroll
  for (int r = 0; r < 16; ++r){
    const float inv = 1.0f / lacc[r];
    const int row = i0 + (r & 3) + 8 * (r >> 2) + 4 * hi;
    u16* dst = aout + (size_t)(bb * 2048 + row) * 1024 + h * 64 + il;
    dst[0]  = f2bf(o0[r] * inv);
    dst[32] = f2bf(o1[r] * inv);
  }
}

// ---------------- launch ----------------
extern "C" void kernel_launch(void* const* d_in, const int* in_sizes, int n_in,
                              void* d_out, int out_size, void* d_ws, size_t ws_size,
                              hipStream_t stream)
{
  const float* x     = (const float*)d_in[0];
  const float* w_in  = (const float*)d_in[1];
  const float* b_in  = (const float*)d_in[2];
  const float* w_out = (const float*)d_in[3];
  const float* b_out = (const float*)d_in[4];
  const int*   cmask = (const int*)d_in[5];

  u16* ws     = (u16*)d_ws;
  u16* xb     = ws;                 // 4096x1024
  u16* winb   = ws + 4194304;       // 3072x1024
  u16* woutb  = ws + 7340032;       // 1024x1024
  u16* qs     = ws + 8388608;       // q,k,v: 3 x [2,16,2048,64]
  u16* attn_o = ws + 20971520;      // 4096x1024

  cvt_kernel<<<4096, 256, 0, stream>>>(x, xb, 4194304);
  cvt_kernel<<<3072, 256, 0, stream>>>(w_in, winb, 3145728);
  cvt_kernel<<<1024, 256, 0, stream>>>(w_out, woutb, 1048576);

  gemm_bt<1><<<dim3(24, 32), 256, 0, stream>>>(xb, winb, b_in, nullptr, qs, 4096, 3072, 1024);

  attn_kernel<<<dim3(32, 32), 128, 0, stream>>>(qs, qs + 4194304, qs + 8388608, attn_o, cmask);

  gemm_bt<0><<<dim3(8, 32), 256, 0, stream>>>(attn_o, woutb, b_out, (float*)d_out, nullptr,
                                              4096, 1024, 1024);
}

// Round 7
// 168.785 us; speedup vs baseline: 1.0424x; 1.0424x over previous
//
#include <hip/hip_runtime.h>

typedef unsigned short u16;
typedef short bfrag __attribute__((ext_vector_type(8)));   // 8 x bf16 (4 VGPRs)
typedef float facc  __attribute__((ext_vector_type(4)));   // 4 x f32
typedef float f16x  __attribute__((ext_vector_type(16)));  // 16 x f32 (32x32 acc)

__device__ __forceinline__ u16 f2bf(float f){
  union { float f; unsigned u; } v; v.f = f;
  unsigned r = v.u + 0x7fffu + ((v.u >> 16) & 1u);
  return (u16)(r >> 16);
}

__device__ __forceinline__ unsigned cvt_pk_bf16(float lo, float hi){
  unsigned d;
  asm("v_cvt_pk_bf16_f32 %0, %1, %2" : "=v"(d) : "v"(lo), "v"(hi));
  return d;
}

__device__ __forceinline__ void gl_lds16(const void* g, void* l){
  __builtin_amdgcn_global_load_lds(
      (const __attribute__((address_space(1))) unsigned int*)g,
      (__attribute__((address_space(3))) unsigned int*)l,
      16, 0, 0);
}

// ---------------- fp32 -> bf16 conversion ----------------
__global__ __launch_bounds__(256) void cvt_kernel(const float* __restrict__ src,
                                                  u16* __restrict__ dst, int n){
  int i = (blockIdx.x * 256 + threadIdx.x) * 4;
  if (i < n){
    float4 f = *(const float4*)(src + i);
    ushort4 o;
    o.x = f2bf(f.x); o.y = f2bf(f.y); o.z = f2bf(f.z); o.w = f2bf(f.w);
    *(ushort4*)(dst + i) = o;
  }
}

// ---------------- bf16 GEMM: C[m,n] = sum_k A[m,k]*B[n,k] + bias[n] ----------------
__device__ __forceinline__ void stage_tile(const u16* __restrict__ G, u16* lds,
                                           int row0, int k0, int K, int tid){
  #pragma unroll
  for (int c = 0; c < 2; ++c){
    int e = c * 2048 + tid * 8;
    int row = e >> 5, col = e & 31;
    gl_lds16(G + (size_t)(row0 + row) * K + k0 + col, lds + c * 2048 + (tid >> 6) * 512);
  }
}

template<int EPI>
__global__ __launch_bounds__(256) void gemm_bt(
    const u16* __restrict__ A, const u16* __restrict__ B,
    const float* __restrict__ bias, float* __restrict__ Cf,
    u16* __restrict__ qkv, int M, int N, int K)
{
  __shared__ u16 Ash[2][4096];
  __shared__ u16 Bsh[2][4096];
  const int tid = threadIdx.x, lane = tid & 63;
  const int w = tid >> 6, wm = w >> 1, wn = w & 1;
  const int cl = lane & 15, g8 = (lane >> 4) * 8;
  const int n0 = blockIdx.x * 128, m0 = blockIdx.y * 128;

  facc acc[4][4];
  #pragma unroll
  for (int mi = 0; mi < 4; ++mi)
    #pragma unroll
    for (int ni = 0; ni < 4; ++ni)
      acc[mi][ni] = (facc){0.f, 0.f, 0.f, 0.f};

  const int NT = K >> 5;
  stage_tile(A, Ash[0], m0, 0, K, tid);
  stage_tile(B, Bsh[0], n0, 0, K, tid);
  __syncthreads();
  int cur = 0;
  for (int kt = 0; kt < NT; ++kt){
    if (kt + 1 < NT){
      stage_tile(A, Ash[cur ^ 1], m0, (kt + 1) << 5, K, tid);
      stage_tile(B, Bsh[cur ^ 1], n0, (kt + 1) << 5, K, tid);
    }
    const u16* As = Ash[cur]; const u16* Bs = Bsh[cur];
    bfrag af[4], bfr[4];
    #pragma unroll
    for (int mi = 0; mi < 4; ++mi)
      af[mi] = *(const bfrag*)&As[(wm * 64 + mi * 16 + cl) * 32 + g8];
    #pragma unroll
    for (int ni = 0; ni < 4; ++ni)
      bfr[ni] = *(const bfrag*)&Bs[(wn * 64 + ni * 16 + cl) * 32 + g8];
    #pragma unroll
    for (int mi = 0; mi < 4; ++mi)
      #pragma unroll
      for (int ni = 0; ni < 4; ++ni)
        acc[mi][ni] = __builtin_amdgcn_mfma_f32_16x16x32_bf16(af[mi], bfr[ni], acc[mi][ni], 0, 0, 0);
    __syncthreads();
    cur ^= 1;
  }

  const int r0 = (lane >> 4) * 4;
  #pragma unroll
  for (int mi = 0; mi < 4; ++mi){
    const int mbase = m0 + wm * 64 + mi * 16 + r0;
    #pragma unroll
    for (int ni = 0; ni < 4; ++ni){
      const int n = n0 + wn * 64 + ni * 16 + cl;
      const float bv = bias[n];
      #pragma unroll
      for (int j = 0; j < 4; ++j){
        float v = acc[mi][ni][j] + bv;
        const int mm = mbase + j;
        if (EPI == 0){
          Cf[(size_t)mm * N + n] = v;
        } else {
          const int part = n >> 10, rest = n & 1023;
          const int h = rest >> 6, d = rest & 63;
          const int bb = mm >> 11, s = mm & 2047;
          // fold 1/sqrt(dh)=1/8 AND log2(e) into q so attention uses exp2 directly
          if (part == 0) v *= 0.18033688011112042f;
          qkv[(size_t)part * 4194304 + (size_t)((bb * 16 + h) * 2048 + s) * 64 + d] = f2bf(v);
        }
      }
    }
  }
}

// ---------------- swapped-role causal flash attention ----------------
// out[i] = sum_{j<=i} softmax_j( Kproj[i] . Qproj[j]*log2e/8 ) * V[j], exp2 domain.
// 4 waves / 64 rows: waves {0,1} handle even j-tiles, {2,3} odd; LDS combine.
__global__ __launch_bounds__(256, 2) void attn_kernel(
    const u16* __restrict__ qarr, const u16* __restrict__ karr,
    const u16* __restrict__ varr, u16* __restrict__ aout,
    const int* __restrict__ cmask)
{
  __shared__ u16 vt[2][2][4096];                // [dbuf][parity][V^T 64x64 swz]
  __shared__ float cO_buf[4096];                // [64 rows][64 d] group-B partial O
  __shared__ float cml[192];                    // [0..63] mB, [64..127] lB, [128..191] mA
  const int tid = threadIdx.x, lane = tid & 63, w = tid >> 6;
  const int il = lane & 31, hi = lane >> 5;
  const int wg = w >> 1, wr = w & 1;            // j-parity group, row half
  const int bh = blockIdx.x;                    // bh -> XCD (K/V/Q L2-resident)
  const int bi = 31 - (int)blockIdx.y;          // heavy tiles dispatch first
  const int i0 = bi * 64;
  const int iw = i0 + wr * 32;                  // this wave's 32-row base
  const u16* Qh = karr + (size_t)bh * 131072;   // output rows come from k-proj
  const u16* Kh = qarr + (size_t)bh * 131072;   // keys are q-proj (pre-scaled)
  const u16* Vh = varr + (size_t)bh * 131072;
  const bool do_mask = (cmask[0] != 0);

  // persistent Q B-frags: bq[kt] holds Q[iw+il][kt*16 + 8*hi + e]
  bfrag bq[4];
  #pragma unroll
  for (int kt = 0; kt < 4; ++kt)
    bq[kt] = *(const bfrag*)(Qh + (size_t)(iw + il) * 64 + kt * 16 + hi * 8);

  f16x o0, o1, lacc;
  #pragma unroll
  for (int r = 0; r < 16; ++r){ o0[r] = 0.f; o1[r] = 0.f; lacc[r] = 0.f; }
  float m_s = -1e30f;

  bfrag ones;
  #pragma unroll
  for (int e = 0; e < 8; ++e) ones[e] = (short)0x3F80;  // bf16 1.0

  const int c8 = lane & 7, jr8 = lane >> 3;     // staging coords (per wave)
  uint4 va[4];
  auto ldV = [&](int tile){                     // wave stages rows wr*32.. of tile
    #pragma unroll
    for (int p = 0; p < 4; ++p)
      va[p] = *(const uint4*)(Vh + (size_t)(tile * 64 + wr * 32 + p * 8 + jr8) * 64 + c8 * 8);
  };
  auto stV = [&](int buf){
    u16* dst = vt[buf][wg];
    #pragma unroll
    for (int p = 0; p < 4; ++p){
      const int j = wr * 32 + p * 8 + jr8;
      const u16* pv = (const u16*)&va[p];
      #pragma unroll
      for (int e = 0; e < 8; ++e){
        const int idx = (e + c8) & 7;           // rotated: conflict-free banks
        const int d = c8 * 8 + idx;             // d&7 == idx
        dst[(d * 64 + j) ^ (idx << 3)] = pv[idx];
      }
    }
  };

  const int njt = do_mask ? (bi + 1) : 32;
  const int nsup = (njt + 1) >> 1;              // super-iterations (2 tiles each)
  ldV(wg); stV(0);
  __syncthreads();
  int cur = 0;

  for (int t = 0; t < nsup; ++t){
    const bool more = (t + 1 < nsup);
    if (more) ldV(2 * t + 2 + wg);              // T14: issue next loads early
    const int jt = 2 * t + wg;
    if (jt < njt){
      // S^T = K . Q^T  (two 32x32 j-subtiles, K straight from global/L2)
      f16x s0, s1;
      #pragma unroll
      for (int r = 0; r < 16; ++r){ s0[r] = 0.f; s1[r] = 0.f; }
      const u16* Kt = Kh + (size_t)jt * 4096;
      __builtin_amdgcn_s_setprio(1);
      #pragma unroll
      for (int kt = 0; kt < 4; ++kt){
        bfrag ak0 = *(const bfrag*)(Kt + (size_t)il * 64 + kt * 16 + hi * 8);
        bfrag ak1 = *(const bfrag*)(Kt + (size_t)(32 + il) * 64 + kt * 16 + hi * 8);
        s0 = __builtin_amdgcn_mfma_f32_32x32x16_bf16(ak0, bq[kt], s0, 0, 0, 0);
        s1 = __builtin_amdgcn_mfma_f32_32x32x16_bf16(ak1, bq[kt], s1, 0, 0, 0);
      }
      __builtin_amdgcn_s_setprio(0);

      if (do_mask && jt == bi){                 // diagonal tile: mask j > i
        const int ib = wr * 32 + il;
        #pragma unroll
        for (int r = 0; r < 16; ++r){
          const int qj = (r & 3) + 8 * (r >> 2) + 4 * hi;
          if (qj > ib)      s0[r] = -1e30f;
          if (qj + 32 > ib) s1[r] = -1e30f;
        }
      }

      // row max: pairwise tree (depth 5) + 1 permlane32_swap
      float tm[16];
      #pragma unroll
      for (int r = 0; r < 16; ++r) tm[r] = fmaxf(s0[r], s1[r]);
      #pragma unroll
      for (int st = 8; st >= 1; st >>= 1)
        #pragma unroll
        for (int r = 0; r < st; ++r) tm[r] = fmaxf(tm[r], tm[r + st]);
      float tmax = tm[0];
      {
        auto tt = __builtin_amdgcn_permlane32_swap(__float_as_uint(tmax),
                                                   __float_as_uint(tmax), false, false);
        tmax = fmaxf(__uint_as_float(tt[0]), __uint_as_float(tt[1]));
      }
      if (__any(tmax - m_s > 8.0f)){            // defer-max (THR=8)
        const float nm = fmaxf(m_s, tmax);
        const float sc = __builtin_amdgcn_exp2f(m_s - nm);
        m_s = nm;
        #pragma unroll
        for (int r = 0; r < 16; ++r){
          const float scb = __shfl(sc, (r & 3) + 8 * (r >> 2) + 4 * hi, 64);
          lacc[r] *= scb; o0[r] *= scb; o1[r] *= scb;
        }
      }
      // P = exp2(S - m), in place
      #pragma unroll
      for (int r = 0; r < 16; ++r) s0[r] = __builtin_amdgcn_exp2f(s0[r] - m_s);
      #pragma unroll
      for (int r = 0; r < 16; ++r) s1[r] = __builtin_amdgcn_exp2f(s1[r] - m_s);

      // T12: cvt_pk + permlane32_swap -> PV A-frags; l via mfma against ones
      #pragma unroll
      for (int kt = 0; kt < 4; ++kt){
        const int q0 = 8 * (kt & 1);
        unsigned a0, a1, b0, b1;
        if (kt < 2){
          a0 = cvt_pk_bf16(s0[q0],     s0[q0 + 1]);
          a1 = cvt_pk_bf16(s0[q0 + 2], s0[q0 + 3]);
          b0 = cvt_pk_bf16(s0[q0 + 4], s0[q0 + 5]);
          b1 = cvt_pk_bf16(s0[q0 + 6], s0[q0 + 7]);
        } else {
          a0 = cvt_pk_bf16(s1[q0],     s1[q0 + 1]);
          a1 = cvt_pk_bf16(s1[q0 + 2], s1[q0 + 3]);
          b0 = cvt_pk_bf16(s1[q0 + 4], s1[q0 + 5]);
          b1 = cvt_pk_bf16(s1[q0 + 6], s1[q0 + 7]);
        }
        auto r0p = __builtin_amdgcn_permlane32_swap(a0, b0, false, false);
        auto r1p = __builtin_amdgcn_permlane32_swap(a1, b1, false, false);
        union { bfrag f; unsigned u[4]; } pa;
        pa.u[0] = r0p[0]; pa.u[1] = r1p[0]; pa.u[2] = r0p[1]; pa.u[3] = r1p[1];

        const int vb = kt * 16 + hi * 8;
        const u16* vcur = vt[cur][wg];
        bfrag v0 = *(const bfrag*)&vcur[(il * 64 + vb) ^ ((il & 7) << 3)];
        bfrag v1 = *(const bfrag*)&vcur[((32 + il) * 64 + vb) ^ ((il & 7) << 3)];
        lacc = __builtin_amdgcn_mfma_f32_32x32x16_bf16(pa.f, ones, lacc, 0, 0, 0);
        __builtin_amdgcn_s_setprio(1);
        o0 = __builtin_amdgcn_mfma_f32_32x32x16_bf16(pa.f, v0, o0, 0, 0, 0);
        o1 = __builtin_amdgcn_mfma_f32_32x32x16_bf16(pa.f, v1, o1, 0, 0, 0);
        __builtin_amdgcn_s_setprio(0);
      }
    }

    if (more){                                  // write prefetched V, one barrier
      stV(cur ^ 1);
      __syncthreads();
      cur ^= 1;
    }
  }

  // ---- combine j-parity partials via dedicated LDS (fully per-row addressed) ----
  __syncthreads();
  if (wg == 1){
    #pragma unroll
    for (int r = 0; r < 16; ++r){
      const int row = wr * 32 + (r & 3) + 8 * (r >> 2) + 4 * hi;
      cO_buf[row * 64 + il]      = o0[r];
      cO_buf[row * 64 + il + 32] = o1[r];
      cml[64 + row] = lacc[r];                  // column-uniform: benign same-value race
    }
    cml[wr * 32 + il] = m_s;                    // lanes il / il+32 hold identical m_s
  } else {
    cml[128 + wr * 32 + il] = m_s;              // group A's own m, via LDS round-trip
  }
  __syncthreads();
  if (wg == 0){
    const int bb = bh >> 4, h = bh & 15;
    #pragma unroll
    for (int r = 0; r < 16; ++r){
      const int rl = (r & 3) + 8 * (r >> 2) + 4 * hi;
      const int row = wr * 32 + rl;
      const float mA = cml[128 + row];
      const float mB = cml[row];
      const float lB = cml[64 + row];
      const float ob0 = cO_buf[row * 64 + il], ob1 = cO_buf[row * 64 + il + 32];
      const float M = fmaxf(mA, mB);
      const float eA = __builtin_amdgcn_exp2f(mA - M);
      const float eB = __builtin_amdgcn_exp2f(mB - M);
      const float inv = 1.0f / (lacc[r] * eA + lB * eB);
      u16* dst = aout + (size_t)(bb * 2048 + i0 + row) * 1024 + h * 64 + il;
      dst[0]  = f2bf((o0[r] * eA + ob0 * eB) * inv);
      dst[32] = f2bf((o1[r] * eA + ob1 * eB) * inv);
    }
  }
}

// ---------------- launch ----------------
extern "C" void kernel_launch(void* const* d_in, const int* in_sizes, int n_in,
                              void* d_out, int out_size, void* d_ws, size_t ws_size,
                              hipStream_t stream)
{
  const float* x     = (const float*)d_in[0];
  const float* w_in  = (const float*)d_in[1];
  const float* b_in  = (const float*)d_in[2];
  const float* w_out = (const float*)d_in[3];
  const float* b_out = (const float*)d_in[4];
  const int*   cmask = (const int*)d_in[5];

  u16* ws     = (u16*)d_ws;
  u16* xb     = ws;                 // 4096x1024
  u16* winb   = ws + 4194304;       // 3072x1024
  u16* woutb  = ws + 7340032;       // 1024x1024
  u16* qs     = ws + 8388608;       // q,k,v: 3 x [2,16,2048,64]
  u16* attn_o = ws + 20971520;      // 4096x1024

  cvt_kernel<<<4096, 256, 0, stream>>>(x, xb, 4194304);
  cvt_kernel<<<3072, 256, 0, stream>>>(w_in, winb, 3145728);
  cvt_kernel<<<1024, 256, 0, stream>>>(w_out, woutb, 1048576);

  gemm_bt<1><<<dim3(24, 32), 256, 0, stream>>>(xb, winb, b_in, nullptr, qs, 4096, 3072, 1024);

  attn_kernel<<<dim3(32, 32), 256, 0, stream>>>(qs, qs + 4194304, qs + 8388608, attn_o, cmask);

  gemm_bt<0><<<dim3(8, 32), 256, 0, stream>>>(attn_o, woutb, b_out, (float*)d_out, nullptr,
                                              4096, 1024, 1024);
}

// Round 8
// 162.834 us; speedup vs baseline: 1.0805x; 1.0365x over previous
//
#include <hip/hip_runtime.h>

typedef unsigned short u16;
typedef short bfrag __attribute__((ext_vector_type(8)));   // 8 x bf16 (4 VGPRs)
typedef float facc  __attribute__((ext_vector_type(4)));   // 4 x f32
typedef float f16x  __attribute__((ext_vector_type(16)));  // 16 x f32 (32x32 acc)

__device__ __forceinline__ u16 f2bf(float f){
  union { float f; unsigned u; } v; v.f = f;
  unsigned r = v.u + 0x7fffu + ((v.u >> 16) & 1u);
  return (u16)(r >> 16);
}

__device__ __forceinline__ unsigned cvt_pk_bf16(float lo, float hi){
  unsigned d;
  asm("v_cvt_pk_bf16_f32 %0, %1, %2" : "=v"(d) : "v"(lo), "v"(hi));
  return d;
}

__device__ __forceinline__ void gl_lds16(const void* g, void* l){
  __builtin_amdgcn_global_load_lds(
      (const __attribute__((address_space(1))) unsigned int*)g,
      (__attribute__((address_space(3))) unsigned int*)l,
      16, 0, 0);
}

// ---------------- fp32 -> bf16 conversion ----------------
__global__ __launch_bounds__(256) void cvt_kernel(const float* __restrict__ src,
                                                  u16* __restrict__ dst, int n){
  int i = (blockIdx.x * 256 + threadIdx.x) * 4;
  if (i < n){
    float4 f = *(const float4*)(src + i);
    ushort4 o;
    o.x = f2bf(f.x); o.y = f2bf(f.y); o.z = f2bf(f.z); o.w = f2bf(f.w);
    *(ushort4*)(dst + i) = o;
  }
}

// ---------------- bf16 GEMM: C[m,n] = sum_k A[m,k]*B[n,k] + bias[n] ----------------
__device__ __forceinline__ void stage_tile(const u16* __restrict__ G, u16* lds,
                                           int row0, int k0, int K, int tid){
  #pragma unroll
  for (int c = 0; c < 2; ++c){
    int e = c * 2048 + tid * 8;
    int row = e >> 5, col = e & 31;
    gl_lds16(G + (size_t)(row0 + row) * K + k0 + col, lds + c * 2048 + (tid >> 6) * 512);
  }
}

template<int EPI>
__global__ __launch_bounds__(256) void gemm_bt(
    const u16* __restrict__ A, const u16* __restrict__ B,
    const float* __restrict__ bias, float* __restrict__ Cf,
    u16* __restrict__ qkv, int M, int N, int K)
{
  __shared__ u16 Ash[2][4096];
  __shared__ u16 Bsh[2][4096];
  const int tid = threadIdx.x, lane = tid & 63;
  const int w = tid >> 6, wm = w >> 1, wn = w & 1;
  const int cl = lane & 15, g8 = (lane >> 4) * 8;
  const int n0 = blockIdx.x * 128, m0 = blockIdx.y * 128;

  facc acc[4][4];
  #pragma unroll
  for (int mi = 0; mi < 4; ++mi)
    #pragma unroll
    for (int ni = 0; ni < 4; ++ni)
      acc[mi][ni] = (facc){0.f, 0.f, 0.f, 0.f};

  const int NT = K >> 5;
  stage_tile(A, Ash[0], m0, 0, K, tid);
  stage_tile(B, Bsh[0], n0, 0, K, tid);
  __syncthreads();
  int cur = 0;
  for (int kt = 0; kt < NT; ++kt){
    if (kt + 1 < NT){
      stage_tile(A, Ash[cur ^ 1], m0, (kt + 1) << 5, K, tid);
      stage_tile(B, Bsh[cur ^ 1], n0, (kt + 1) << 5, K, tid);
    }
    const u16* As = Ash[cur]; const u16* Bs = Bsh[cur];
    bfrag af[4], bfr[4];
    #pragma unroll
    for (int mi = 0; mi < 4; ++mi)
      af[mi] = *(const bfrag*)&As[(wm * 64 + mi * 16 + cl) * 32 + g8];
    #pragma unroll
    for (int ni = 0; ni < 4; ++ni)
      bfr[ni] = *(const bfrag*)&Bs[(wn * 64 + ni * 16 + cl) * 32 + g8];
    #pragma unroll
    for (int mi = 0; mi < 4; ++mi)
      #pragma unroll
      for (int ni = 0; ni < 4; ++ni)
        acc[mi][ni] = __builtin_amdgcn_mfma_f32_16x16x32_bf16(af[mi], bfr[ni], acc[mi][ni], 0, 0, 0);
    __syncthreads();
    cur ^= 1;
  }

  const int r0 = (lane >> 4) * 4;
  #pragma unroll
  for (int mi = 0; mi < 4; ++mi){
    const int mbase = m0 + wm * 64 + mi * 16 + r0;
    #pragma unroll
    for (int ni = 0; ni < 4; ++ni){
      const int n = n0 + wn * 64 + ni * 16 + cl;
      const float bv = bias[n];
      #pragma unroll
      for (int j = 0; j < 4; ++j){
        float v = acc[mi][ni][j] + bv;
        const int mm = mbase + j;
        if (EPI == 0){
          Cf[(size_t)mm * N + n] = v;
        } else {
          const int part = n >> 10, rest = n & 1023;
          const int h = rest >> 6, d = rest & 63;
          const int bb = mm >> 11, s = mm & 2047;
          // fold 1/sqrt(dh)=1/8 AND log2(e) into q so attention uses exp2 directly
          if (part == 0) v *= 0.18033688011112042f;
          qkv[(size_t)part * 4194304 + (size_t)((bb * 16 + h) * 2048 + s) * 64 + d] = f2bf(v);
        }
      }
    }
  }
}

// ---------------- swapped-role causal flash attention ----------------
// out[i] = sum_{j<=i} softmax_j( Kproj[i] . Qproj[j]*log2e/8 ) * V[j], exp2 domain.
// Block: 128 q-rows, 4 waves x 32 rows; K,V tiles staged once in LDS and
// shared by all waves (j-tiles walked jointly). S^T = mfma(K, Q): lane
// (hi,il) holds S[j=qj(r)][i=il]; P stays in registers (T12).
__global__ __launch_bounds__(256, 2) void attn_kernel(
    const u16* __restrict__ qarr, const u16* __restrict__ karr,
    const u16* __restrict__ varr, u16* __restrict__ aout,
    const int* __restrict__ cmask)
{
  __shared__ u16 k_sw[2][4096];                 // K [j][d] XOR-swizzled, dbuf
  __shared__ u16 v_sw[2][4096];                 // V^T [d][j] XOR-swizzled, dbuf
  const int tid = threadIdx.x, lane = tid & 63, w = tid >> 6;
  const int il = lane & 31, hi = lane >> 5;
  const int bh = blockIdx.x;                    // bh -> XCD (K/V/Q L2-resident)
  const int bi = 15 - (int)blockIdx.y;          // heavy row-blocks dispatch first
  const int i0 = bi * 128;
  const int iw = i0 + w * 32;                   // this wave's 32-row base
  const u16* Qh = karr + (size_t)bh * 131072;   // output rows come from k-proj
  const u16* Kh = qarr + (size_t)bh * 131072;   // keys are q-proj (pre-scaled)
  const u16* Vh = varr + (size_t)bh * 131072;
  const bool do_mask = (cmask[0] != 0);
  const int my_diag = iw >> 6;                  // wave's diagonal j-tile

  // persistent Q B-frags: bq[kt] holds Q[iw+il][kt*16 + 8*hi + e]
  bfrag bq[4];
  #pragma unroll
  for (int kt = 0; kt < 4; ++kt)
    bq[kt] = *(const bfrag*)(Qh + (size_t)(iw + il) * 64 + kt * 16 + hi * 8);

  f16x o0, o1;
  #pragma unroll
  for (int r = 0; r < 16; ++r){ o0[r] = 0.f; o1[r] = 0.f; }
  float m_s = -1e30f, l_s = 0.f;

  // staging (256 threads, 2 passes of 32 rows each for K and V)
  const int c8 = tid & 7, r8 = tid >> 3;        // r8 in 0..31
  uint4 ka[2], va[2];
  auto ldKV = [&](int tile){
    #pragma unroll
    for (int p = 0; p < 2; ++p){
      ka[p] = *(const uint4*)(Kh + (size_t)(tile * 64 + p * 32 + r8) * 64 + c8 * 8);
      va[p] = *(const uint4*)(Vh + (size_t)(tile * 64 + p * 32 + r8) * 64 + c8 * 8);
    }
  };
  auto stKV = [&](int buf){
    #pragma unroll
    for (int p = 0; p < 2; ++p){
      const int row = p * 32 + r8;
      *(uint4*)&k_sw[buf][(row * 64 + c8 * 8) ^ ((row & 7) << 3)] = ka[p];
      const u16* pv = (const u16*)&va[p];
      #pragma unroll
      for (int e = 0; e < 8; ++e){
        const int idx = (e + c8) & 7;           // rotated: conflict-free banks
        const int d = c8 * 8 + idx;             // d&7 == idx
        v_sw[buf][(d * 64 + row) ^ (idx << 3)] = pv[idx];
      }
    }
  };

  const int njt = do_mask ? (2 * bi + 2) : 32;
  ldKV(0); stKV(0);
  __syncthreads();
  int cur = 0;

  for (int jt = 0; jt < njt; ++jt){
    const bool more = (jt + 1 < njt);
    if (more) ldKV(jt + 1);                     // T14: issue next loads early
    const bool live = (!do_mask) || (jt <= my_diag);   // wave-uniform
    if (live){
      // S^T = K . Q^T  (two 32x32 j-subtiles; K from swizzled LDS)
      f16x s0, s1;
      #pragma unroll
      for (int r = 0; r < 16; ++r){ s0[r] = 0.f; s1[r] = 0.f; }
      const u16* kc = k_sw[cur];
      __builtin_amdgcn_s_setprio(1);
      #pragma unroll
      for (int kt = 0; kt < 4; ++kt){
        const int vb = kt * 16 + hi * 8;
        bfrag ak0 = *(const bfrag*)&kc[(il * 64 + vb) ^ ((il & 7) << 3)];
        bfrag ak1 = *(const bfrag*)&kc[((32 + il) * 64 + vb) ^ ((il & 7) << 3)];
        s0 = __builtin_amdgcn_mfma_f32_32x32x16_bf16(ak0, bq[kt], s0, 0, 0, 0);
        s1 = __builtin_amdgcn_mfma_f32_32x32x16_bf16(ak1, bq[kt], s1, 0, 0, 0);
      }
      __builtin_amdgcn_s_setprio(0);

      if (do_mask && jt == my_diag){            // diagonal tile: mask j > i
        const int ib = (w & 1) * 32 + il;
        #pragma unroll
        for (int r = 0; r < 16; ++r){
          const int qj = (r & 3) + 8 * (r >> 2) + 4 * hi;
          if (qj > ib)      s0[r] = -1e30f;
          if (qj + 32 > ib) s1[r] = -1e30f;
        }
      }

      // row max: pairwise tree (depth 5) + 1 permlane32_swap
      float tm[16];
      #pragma unroll
      for (int r = 0; r < 16; ++r) tm[r] = fmaxf(s0[r], s1[r]);
      #pragma unroll
      for (int st = 8; st >= 1; st >>= 1)
        #pragma unroll
        for (int r = 0; r < st; ++r) tm[r] = fmaxf(tm[r], tm[r + st]);
      float tmax = tm[0];
      {
        auto tt = __builtin_amdgcn_permlane32_swap(__float_as_uint(tmax),
                                                   __float_as_uint(tmax), false, false);
        tmax = fmaxf(__uint_as_float(tt[0]), __uint_as_float(tt[1]));
      }
      if (__any(tmax - m_s > 8.0f)){            // defer-max (THR=8)
        const float nm = fmaxf(m_s, tmax);
        const float sc = __builtin_amdgcn_exp2f(m_s - nm);
        m_s = nm; l_s *= sc;
        #pragma unroll
        for (int r = 0; r < 16; ++r){
          const float scb = __shfl(sc, (r & 3) + 8 * (r >> 2) + 4 * hi, 64);
          o0[r] *= scb; o1[r] *= scb;
        }
      }
      // P = exp2(S - m) in place; l as per-lane scalar (row = il)
      float rsum = 0.f;
      #pragma unroll
      for (int r = 0; r < 16; ++r){ s0[r] = __builtin_amdgcn_exp2f(s0[r] - m_s); rsum += s0[r]; }
      #pragma unroll
      for (int r = 0; r < 16; ++r){ s1[r] = __builtin_amdgcn_exp2f(s1[r] - m_s); rsum += s1[r]; }
      {
        auto rr = __builtin_amdgcn_permlane32_swap(__float_as_uint(rsum),
                                                   __float_as_uint(rsum), false, false);
        rsum = __uint_as_float(rr[0]) + __uint_as_float(rr[1]);
      }
      l_s += rsum;

      // T12: cvt_pk + permlane32_swap -> PV A-frags
      const u16* vcur = v_sw[cur];
      #pragma unroll
      for (int kt = 0; kt < 4; ++kt){
        const int q0 = 8 * (kt & 1);
        unsigned a0, a1, b0, b1;
        if (kt < 2){
          a0 = cvt_pk_bf16(s0[q0],     s0[q0 + 1]);
          a1 = cvt_pk_bf16(s0[q0 + 2], s0[q0 + 3]);
          b0 = cvt_pk_bf16(s0[q0 + 4], s0[q0 + 5]);
          b1 = cvt_pk_bf16(s0[q0 + 6], s0[q0 + 7]);
        } else {
          a0 = cvt_pk_bf16(s1[q0],     s1[q0 + 1]);
          a1 = cvt_pk_bf16(s1[q0 + 2], s1[q0 + 3]);
          b0 = cvt_pk_bf16(s1[q0 + 4], s1[q0 + 5]);
          b1 = cvt_pk_bf16(s1[q0 + 6], s1[q0 + 7]);
        }
        auto r0p = __builtin_amdgcn_permlane32_swap(a0, b0, false, false);
        auto r1p = __builtin_amdgcn_permlane32_swap(a1, b1, false, false);
        union { bfrag f; unsigned u[4]; } pa;
        pa.u[0] = r0p[0]; pa.u[1] = r1p[0]; pa.u[2] = r0p[1]; pa.u[3] = r1p[1];

        const int vb = kt * 16 + hi * 8;
        bfrag v0 = *(const bfrag*)&vcur[(il * 64 + vb) ^ ((il & 7) << 3)];
        bfrag v1 = *(const bfrag*)&vcur[((32 + il) * 64 + vb) ^ ((il & 7) << 3)];
        __builtin_amdgcn_s_setprio(1);
        o0 = __builtin_amdgcn_mfma_f32_32x32x16_bf16(pa.f, v0, o0, 0, 0, 0);
        o1 = __builtin_amdgcn_mfma_f32_32x32x16_bf16(pa.f, v1, o1, 0, 0, 0);
        __builtin_amdgcn_s_setprio(0);
      }
    }

    if (more){                                  // write prefetched tile, one barrier
      stKV(cur ^ 1);
      __syncthreads();
      cur ^= 1;
    }
  }

  // epilogue: o0[r] = O[iw+qj(r)][il], o1 -> d=32+il; 1/l broadcast from lane qj
  const float inv = 1.0f / l_s;                 // valid at lanes with il == row
  const int bb = bh >> 4, h = bh & 15;
  #pragma unroll
  for (int r = 0; r < 16; ++r){
    const int qj = (r & 3) + 8 * (r >> 2) + 4 * hi;
    const float invr = __shfl(inv, qj, 64);
    const int row = iw + qj;
    u16* dst = aout + (size_t)(bb * 2048 + row) * 1024 + h * 64 + il;
    dst[0]  = f2bf(o0[r] * invr);
    dst[32] = f2bf(o1[r] * invr);
  }
}

// ---------------- launch ----------------
extern "C" void kernel_launch(void* const* d_in, const int* in_sizes, int n_in,
                              void* d_out, int out_size, void* d_ws, size_t ws_size,
                              hipStream_t stream)
{
  const float* x     = (const float*)d_in[0];
  const float* w_in  = (const float*)d_in[1];
  const float* b_in  = (const float*)d_in[2];
  const float* w_out = (const float*)d_in[3];
  const float* b_out = (const float*)d_in[4];
  const int*   cmask = (const int*)d_in[5];

  u16* ws     = (u16*)d_ws;
  u16* xb     = ws;                 // 4096x1024
  u16* winb   = ws + 4194304;       // 3072x1024
  u16* woutb  = ws + 7340032;       // 1024x1024
  u16* qs     = ws + 8388608;       // q,k,v: 3 x [2,16,2048,64]
  u16* attn_o = ws + 20971520;      // 4096x1024

  cvt_kernel<<<4096, 256, 0, stream>>>(x, xb, 4194304);
  cvt_kernel<<<3072, 256, 0, stream>>>(w_in, winb, 3145728);
  cvt_kernel<<<1024, 256, 0, stream>>>(w_out, woutb, 1048576);

  gemm_bt<1><<<dim3(24, 32), 256, 0, stream>>>(xb, winb, b_in, nullptr, qs, 4096, 3072, 1024);

  attn_kernel<<<dim3(32, 16), 256, 0, stream>>>(qs, qs + 4194304, qs + 8388608, attn_o, cmask);

  gemm_bt<0><<<dim3(8, 32), 256, 0, stream>>>(attn_o, woutb, b_out, (float*)d_out, nullptr,
                                              4096, 1024, 1024);
}